// Round 4
// baseline (33.875 us; speedup 1.0000x reference)
//
#include <hip/hip_runtime.h>

// 8 rows per 64-lane wave. Each row owns an 8-lane group:
//   group-lane j in 0..3 : float4 load of row[j*4 .. j*4+3]         (front 16)
//   group-lane j in 4..7 : float4 load of row[D-16+(j-4)*4 .. +3]   (back 16)
// Per-lane 4-bit sign mask -> local first/last -> 3-step __shfl_xor min/max
// reduce within the 8-lane group (xor partners 1,2,4 stay in-group).
// P(no x>=0 in 16 N(0,1) samples) = 2^-16 per end -> expect ~2 fallback rows
// per launch; the fallback full-row group scan is correct for any data.
__global__ __launch_bounds__(256) void nby2_reverse_kernel(
        const float* __restrict__ x,
        const int* __restrict__ vrange_p,
        float* __restrict__ out,
        int N, int D) {
    const int lane   = threadIdx.x & 63;
    const int wave   = (blockIdx.x * blockDim.x + threadIdx.x) >> 6;
    const int g      = lane >> 3;     // row-group within wave (0..7)
    const int j      = lane & 7;      // lane within group
    const int row_id = wave * 8 + g;
    if (row_id >= N) return;

    const int vr = *vrange_p;         // uniform scalar load
    const float* __restrict__ row = x + (size_t)row_id * (size_t)D;

    const int BIG = 0x7fffffff;
    int fval = BIG;                   // candidate 'first'
    int lval = -1;                    // candidate 'last'

    if (D >= 32 && (D & 3) == 0) {
        // ---- fast probe: front 16 + back 16 elements, one float4 per lane --
        const int base = (j < 4) ? (j * 4) : (D - 16 + (j - 4) * 4);
        const float4 v = *reinterpret_cast<const float4*>(row + base);
        unsigned m = (v.x >= 0.f ? 1u : 0u) | (v.y >= 0.f ? 2u : 0u)
                   | (v.z >= 0.f ? 4u : 0u) | (v.w >= 0.f ? 8u : 0u);
        if (j < 4) {
            if (m) fval = base + __builtin_ctz(m);
        } else {
            if (m) lval = base + 31 - __builtin_clz(m);  // + highest set bit
        }
        #pragma unroll
        for (int d = 1; d < 8; d <<= 1) {
            fval = min(fval, __shfl_xor(fval, d));
            lval = max(lval, __shfl_xor(lval, d));
        }
    }

    if (fval == BIG || lval < 0) {    // group-uniform condition
        // ---- rare fallback: full row scan by the 8-lane group ----
        int lf = BIG, ll = -1;
        for (int i = j; i < D; i += 8) {
            if (row[i] >= 0.f) { lf = min(lf, i); ll = max(ll, i); }
        }
        #pragma unroll
        for (int d = 1; d < 8; d <<= 1) {
            lf = min(lf, __shfl_xor(lf, d));
            ll = max(ll, __shfl_xor(ll, d));
        }
        fval = min(fval, lf);
        lval = max(lval, ll);
        if (fval == BIG) {            // all-negative row
            if (j == 0) out[row_id] = 0.0f;
            return;
        }
    }

    if (j == 0) {
        const int bits = vr >> 1;
        out[row_id] = (float)(2 * bits - fval - lval - 1);
    }
}

extern "C" void kernel_launch(void* const* d_in, const int* in_sizes, int n_in,
                              void* d_out, int out_size, void* d_ws, size_t ws_size,
                              hipStream_t stream) {
    const float* x = (const float*)d_in[0];
    const int* vrange_p = (const int*)d_in[1];
    float* out = (float*)d_out;

    const int N = out_size;                   // 65536 rows
    const int D = in_sizes[0] / out_size;     // 2048 cols

    const int rows_per_block = 32;            // 4 waves * 8 rows = 256 threads
    const int grid = (N + rows_per_block - 1) / rows_per_block;

    nby2_reverse_kernel<<<grid, 256, 0, stream>>>(x, vrange_p, out, N, D);
}

// Round 5
// 23.887 us; speedup vs baseline: 1.4181x; 1.4181x over previous
//
#include <hip/hip_runtime.h>

// 8 rows per 64-lane wave. Each row owns an 8-lane group:
//   group-lane j in 0..3 : float4 load of row[j*4 .. j*4+3]         (front 16)
//   group-lane j in 4..7 : float4 load of row[D-16+(j-4)*4 .. +3]   (back 16)
// P(no x>=0 in 16 N(0,1) samples) = 2^-16 per end -> ~2 of 65536 rows take
// the fallback. Round-4 lesson: the fallback MUST be fast (vectorized,
// 32 elems/iter, independent loads) so the straggler wave hides under the
// bulk; a scalar stride-8 fallback cost ~25us of tail latency.
__global__ __launch_bounds__(256) void nby2_reverse_kernel(
        const float* __restrict__ x,
        const int* __restrict__ vrange_p,
        float* __restrict__ out,
        int N, int D) {
    const int lane   = threadIdx.x & 63;
    const int wave   = (blockIdx.x * blockDim.x + threadIdx.x) >> 6;
    const int g      = lane >> 3;     // row-group within wave (0..7)
    const int j      = lane & 7;      // lane within group
    const int row_id = wave * 8 + g;
    if (row_id >= N) return;

    const int vr = *vrange_p;         // uniform scalar load, issued early
    const float* __restrict__ row = x + (size_t)row_id * (size_t)D;

    const int BIG = 0x7fffffff;
    int fval = BIG;                   // candidate 'first'
    int lval = -1;                    // candidate 'last'
    const bool vec_ok = ((D & 3) == 0);   // float4-aligned rows

    if (D >= 32 && vec_ok) {
        // ---- fast probe: front 16 + back 16 elements, one float4 per lane --
        const int base = (j < 4) ? (j * 4) : (D - 16 + (j - 4) * 4);
        const float4 v = *reinterpret_cast<const float4*>(row + base);
        const unsigned m = (v.x >= 0.f ? 1u : 0u) | (v.y >= 0.f ? 2u : 0u)
                         | (v.z >= 0.f ? 4u : 0u) | (v.w >= 0.f ? 8u : 0u);
        if (m) {
            if (j < 4) fval = base + __builtin_ctz(m);
            else       lval = base + 31 - __builtin_clz(m);
        }
        #pragma unroll
        for (int d = 1; d < 8; d <<= 1) {
            fval = min(fval, __shfl_xor(fval, d));
            lval = max(lval, __shfl_xor(lval, d));
        }
    }

    if (fval == BIG || lval < 0) {    // group-uniform: rare fallback
        int lf = BIG, ll = -1;
        if (vec_ok) {
            // Vectorized full-row scan: 8 lanes x float4 = 32 elems/iter.
            const int T = D & ~31;    // largest multiple of 32 <= D
            for (int i = j * 4; i < T; i += 32) {
                const float4 v = *reinterpret_cast<const float4*>(row + i);
                const unsigned m = (v.x >= 0.f ? 1u : 0u) | (v.y >= 0.f ? 2u : 0u)
                                 | (v.z >= 0.f ? 4u : 0u) | (v.w >= 0.f ? 8u : 0u);
                if (m) {
                    lf = min(lf, i + __builtin_ctz(m));
                    ll = max(ll, i + 31 - __builtin_clz(m));
                }
            }
            for (int i = T + j; i < D; i += 8) {          // scalar tail (<32)
                if (row[i] >= 0.f) { lf = min(lf, i); ll = max(ll, i); }
            }
        } else {
            for (int i = j; i < D; i += 8) {              // generic path
                if (row[i] >= 0.f) { lf = min(lf, i); ll = max(ll, i); }
            }
        }
        #pragma unroll
        for (int d = 1; d < 8; d <<= 1) {
            lf = min(lf, __shfl_xor(lf, d));
            ll = max(ll, __shfl_xor(ll, d));
        }
        fval = min(fval, lf);
        lval = max(lval, ll);
        if (fval == BIG) {            // all-negative row
            if (j == 0) out[row_id] = 0.0f;
            return;
        }
    }

    if (j == 0) {
        const int bits = vr >> 1;
        out[row_id] = (float)(2 * bits - fval - lval - 1);
    }
}

extern "C" void kernel_launch(void* const* d_in, const int* in_sizes, int n_in,
                              void* d_out, int out_size, void* d_ws, size_t ws_size,
                              hipStream_t stream) {
    const float* x = (const float*)d_in[0];
    const int* vrange_p = (const int*)d_in[1];
    float* out = (float*)d_out;

    const int N = out_size;                   // 65536 rows
    const int D = in_sizes[0] / out_size;     // 2048 cols

    const int rows_per_block = 32;            // 4 waves * 8 rows = 256 threads
    const int grid = (N + rows_per_block - 1) / rows_per_block;

    nby2_reverse_kernel<<<grid, 256, 0, stream>>>(x, vrange_p, out, N, D);
}

// Round 6
// 9.417 us; speedup vs baseline: 3.5972x; 2.5366x over previous
//
#include <hip/hip_runtime.h>

// 8 rows per 64-lane wave; 8-lane group per row; TWO independent float4
// loads per lane so each end is probed 32 elements wide:
//   lanes j=0..3 : row[j*4 .. j*4+3]  and  row[16+j*4 .. 16+j*4+3]   (0..31)
//   lanes j=4..7 : row[D-32+(j-4)*4 ..] and row[D-16+(j-4)*4 ..]  (D-32..D-1)
// P(no x>=0 in 32 N(0,1) samples) = 2^-32 per end -> the fallback runs with
// probability ~3e-5 PER LAUNCH. Rounds 4/5 lesson: a fallback that ever runs
// costs ~24us of straggler latency (the compiler serializes the scan loop's
// loads, one HBM round-trip per iteration) -- so make it unreachable in
// practice, not fast.
__global__ __launch_bounds__(256) void nby2_reverse_kernel(
        const float* __restrict__ x,
        const int* __restrict__ vrange_p,
        float* __restrict__ out,
        int N, int D) {
    const int lane   = threadIdx.x & 63;
    const int wave   = (blockIdx.x * blockDim.x + threadIdx.x) >> 6;
    const int g      = lane >> 3;     // row-group within wave (0..7)
    const int j      = lane & 7;      // lane within group
    const int row_id = wave * 8 + g;
    if (row_id >= N) return;

    const int vr = *vrange_p;         // uniform scalar load, issued early
    const float* __restrict__ row = x + (size_t)row_id * (size_t)D;

    const int BIG = 0x7fffffff;
    int fval = BIG;                   // candidate 'first'
    int lval = -1;                    // candidate 'last'
    const bool vec_ok = ((D & 3) == 0);

    if (D >= 32 && vec_ok) {
        // Two independent 16B loads per lane -> both in flight together.
        int base0, base1;
        if (j < 4) { base0 = j * 4;               base1 = 16 + j * 4; }
        else       { base0 = D - 32 + (j - 4)*4;  base1 = D - 16 + (j - 4)*4; }
        // For D in [32,64) segments may overlap row middle; still correct
        // (coverage is a superset union; indices computed absolutely).
        const float4 v0 = *reinterpret_cast<const float4*>(row + base0);
        const float4 v1 = *reinterpret_cast<const float4*>(row + base1);
        const unsigned m0 = (v0.x >= 0.f ? 1u : 0u) | (v0.y >= 0.f ? 2u : 0u)
                          | (v0.z >= 0.f ? 4u : 0u) | (v0.w >= 0.f ? 8u : 0u);
        const unsigned m1 = (v1.x >= 0.f ? 1u : 0u) | (v1.y >= 0.f ? 2u : 0u)
                          | (v1.z >= 0.f ? 4u : 0u) | (v1.w >= 0.f ? 8u : 0u);
        if (j < 4) {   // first: prefer earlier segment (base0 < base1)
            if (m0)      fval = base0 + __builtin_ctz(m0);
            else if (m1) fval = base1 + __builtin_ctz(m1);
        } else {       // last: prefer later segment (base1 > base0)
            if (m1)      lval = base1 + 31 - __builtin_clz(m1);
            else if (m0) lval = base0 + 31 - __builtin_clz(m0);
        }
        #pragma unroll
        for (int d = 1; d < 8; d <<= 1) {
            fval = min(fval, __shfl_xor(fval, d));
            lval = max(lval, __shfl_xor(lval, d));
        }
    }

    if (fval == BIG || lval < 0) {    // group-uniform; ~never taken
        int lf = BIG, ll = -1;
        if (vec_ok) {
            const int T = D & ~31;
            for (int i = j * 4; i < T; i += 32) {
                const float4 v = *reinterpret_cast<const float4*>(row + i);
                const unsigned m = (v.x >= 0.f ? 1u : 0u) | (v.y >= 0.f ? 2u : 0u)
                                 | (v.z >= 0.f ? 4u : 0u) | (v.w >= 0.f ? 8u : 0u);
                if (m) {
                    lf = min(lf, i + __builtin_ctz(m));
                    ll = max(ll, i + 31 - __builtin_clz(m));
                }
            }
            for (int i = T + j; i < D; i += 8) {
                if (row[i] >= 0.f) { lf = min(lf, i); ll = max(ll, i); }
            }
        } else {
            for (int i = j; i < D; i += 8) {
                if (row[i] >= 0.f) { lf = min(lf, i); ll = max(ll, i); }
            }
        }
        #pragma unroll
        for (int d = 1; d < 8; d <<= 1) {
            lf = min(lf, __shfl_xor(lf, d));
            ll = max(ll, __shfl_xor(ll, d));
        }
        fval = min(fval, lf);
        lval = max(lval, ll);
        if (fval == BIG) {            // all-negative row
            if (j == 0) out[row_id] = 0.0f;
            return;
        }
    }

    if (j == 0) {
        const int bits = vr >> 1;
        out[row_id] = (float)(2 * bits - fval - lval - 1);
    }
}

extern "C" void kernel_launch(void* const* d_in, const int* in_sizes, int n_in,
                              void* d_out, int out_size, void* d_ws, size_t ws_size,
                              hipStream_t stream) {
    const float* x = (const float*)d_in[0];
    const int* vrange_p = (const int*)d_in[1];
    float* out = (float*)d_out;

    const int N = out_size;                   // 65536 rows
    const int D = in_sizes[0] / out_size;     // 2048 cols

    const int rows_per_block = 32;            // 4 waves * 8 rows = 256 threads
    const int grid = (N + rows_per_block - 1) / rows_per_block;

    nby2_reverse_kernel<<<grid, 256, 0, stream>>>(x, vrange_p, out, N, D);
}